// Round 8
// baseline (244.188 us; speedup 1.0000x reference)
//
#include <hip/hip_runtime.h>
#include <stdint.h>

// Depthwise causal conv1d, channel-last. x:(B,L,D) f32, w:(K,1,D), b:(D), y:(B,L,D).
// y[n,l,d] = sum_k w[k,d]*x[n,l+k-3,d] + b[d], zero-padded left.
//
// R12: CONTIGUOUS flat streaming (copy + 4-tap FIR). Pattern theory:
// R6/R9/R11 (LDS ring, register ring, gload_lds ping-pong; 10x MLP spread)
// all pinned at 72-82 us / 2.6-3.7 TB/s, while fillBufferAligned does
// 6.7 TB/s at 9.5% occupancy. Common factor of the slow kernels: 1 KB
// column-strip accesses at 8 KB row stride (poor DRAM page sequentiality).
// Fix: flatten. y_flat[i] = w3[d]x[i] + w2[d]x[i-D] + w1[d]x[i-2D]
//               + w0[d]x[i-3D] + b[d],  d = i mod D.
// One contiguous read stream + one contiguous write stream (= m13 copy
// pattern); the 3 taps at -8/-16/-24 KB are L2 hits because a chunked XCD
// swizzle gives each XCD a contiguous region (neighboring rows processed
// by same-XCD blocks at the same time). Weights loaded once per thread
// (grid step is a multiple of D -> fixed channel group). No LDS, no
// barriers; ~50 VGPR -> 32 waves/CU; TLP hides all latency.

#define CB 4
#define CL 4096
#define CD 2048
#define D4 (CD / 4)                 // 512 float4 per row
#define NF4 (CB * CL * CD / 4)      // 8388608 total float4
#define BLK 256
#define GRID 2048
#define STEP (BLK * GRID)           // f4 per sweep step (multiple of D4)
#define STEPS (NF4 / STEP)          // 16

typedef float nfloat4 __attribute__((ext_vector_type(4)));

__global__ __launch_bounds__(256) void short_conv_kernel(
    const float* __restrict__ x,
    const float* __restrict__ w,
    const float* __restrict__ bias,
    float* __restrict__ y)
{
    const int tid = threadIdx.x;

    // Chunked XCD swizzle: HW assigns XCD = blockIdx % 8 (round-robin).
    // wid = (bid&7)*256 + bid>>3 gives each XCD a CONTIGUOUS 256-block
    // chunk of the flat sweep -> tap reads hit that XCD's own L2.
    const int wid = (blockIdx.x & 7) * (GRID / 8) + (blockIdx.x >> 3);

    const int base4 = wid * BLK + tid;      // this thread's f4 index at step 0
    const int d4    = base4 & (D4 - 1);     // fixed channel group (f4 units)

    // Per-thread weights/bias for channels d4*4 .. +3 (loaded once, L2-tiny).
    const float4 w0 = *(const float4*)(w + 0 * CD + d4 * 4);
    const float4 w1 = *(const float4*)(w + 1 * CD + d4 * 4);
    const float4 w2 = *(const float4*)(w + 2 * CD + d4 * 4);
    const float4 w3 = *(const float4*)(w + 3 * CD + d4 * 4);
    const float4 bv = *(const float4*)(bias + d4 * 4);

    const float4* xf = (const float4*)x;
    float*        yf = y;

#pragma unroll 2
    for (int s = 0; s < STEPS; ++s) {
        const int i4 = base4 + s * STEP;           // flat f4 index
        const int lb = (i4 >> 9) & (CL - 1);       // row within batch

        const float4* xp = xf + i4;

        float4 x0 = xp[0];
        float4 xm1, xm2, xm3;
        if (lb >= 3) {                              // block-uniform branch
            xm1 = xp[-1 * D4];
            xm2 = xp[-2 * D4];
            xm3 = xp[-3 * D4];
        } else {                                    // first 3 rows of a batch
            const float4 z = make_float4(0.f, 0.f, 0.f, 0.f);
            xm1 = (lb >= 1) ? xp[-1 * D4] : z;
            xm2 = (lb >= 2) ? xp[-2 * D4] : z;
            xm3 = z;
        }

        nfloat4 r;
        r.x = fmaf(w0.x, xm3.x, fmaf(w1.x, xm2.x, fmaf(w2.x, xm1.x, fmaf(w3.x, x0.x, bv.x))));
        r.y = fmaf(w0.y, xm3.y, fmaf(w1.y, xm2.y, fmaf(w2.y, xm1.y, fmaf(w3.y, x0.y, bv.y))));
        r.z = fmaf(w0.z, xm3.z, fmaf(w1.z, xm2.z, fmaf(w2.z, xm1.z, fmaf(w3.z, x0.z, bv.z))));
        r.w = fmaf(w0.w, xm3.w, fmaf(w1.w, xm2.w, fmaf(w2.w, xm1.w, fmaf(w3.w, x0.w, bv.w))));

        __builtin_nontemporal_store(r, (nfloat4*)(yf + (size_t)i4 * 4));
    }
}

extern "C" void kernel_launch(void* const* d_in, const int* in_sizes, int n_in,
                              void* d_out, int out_size, void* d_ws, size_t ws_size,
                              hipStream_t stream) {
    const float* x = (const float*)d_in[0];
    const float* w = (const float*)d_in[1];
    const float* b = (const float*)d_in[2];
    float* y = (float*)d_out;

    short_conv_kernel<<<GRID, BLK, 0, stream>>>(x, w, b, y);
}

// Round 9
// 229.088 us; speedup vs baseline: 1.0659x; 1.0659x over previous
//
#include <hip/hip_runtime.h>
#include <stdint.h>

// Depthwise causal conv1d, channel-last. x:(B,L,D) f32, w:(K,1,D), b:(D), y:(B,L,D).
// y[n,l,d] = sum_k w[k,d]*x[n,l+k-3,d] + b[d], zero-padded left.
//
// R13: REVERT to the R0 champion (measured 229.7 us total; conv < 79 us).
// Session post-mortem: five structural alternatives -- wave-private LDS ring
// (R6, 80.7), register ring (R9, 80.4; collapsed by regalloc to VGPR=40),
// gload_lds ping-pong (R11, 82.1), flat contiguous stream (R12, 87.0) --
// spanning occupancy 9->61%, MLP ~1->16, strip->contiguous patterns, ALL land
// in a 72-87 us band and ALL lose to this bulk-sync structure. No counter
// saturates (HBM <= 3.7 TB/s, VALU <= 5%, conflicts 0): the op sits on an
// effective L2-boundary traffic floor shared with the harness fills. Keep the
// empirical champion.
//
// Structure: stage 35 row-strips (32 output rows + 3 causal halo) of a 1 KB
// channel strip into LDS via global_load_lds (width 16, fire-and-forget, no
// dest VGPRs -- cannot be sunk by the register allocator), one barrier, then
// each wave computes 8 rows with a register sliding window and nontemporal
// float4 stores. 35 KB LDS -> 4 blocks/CU.

#define CB 4
#define CL 4096
#define CD 2048
#define STRIP 256               // floats per channel strip (1 KB per row-strip)
#define SF4 (STRIP / 4)         // 64 float4 per row-strip = one wave-load
#define ROWS 32                 // output rows per block
#define HALO 3
#define LROWS (ROWS + HALO)     // 35 staged rows
#define NSTRIP (CD / STRIP)     // 8
#define NCHUNK (CL / ROWS)      // 128

typedef float nfloat4 __attribute__((ext_vector_type(4)));

__global__ __launch_bounds__(256) void short_conv_kernel(
    const float* __restrict__ x,
    const float* __restrict__ w,
    const float* __restrict__ bias,
    float* __restrict__ y)
{
    __shared__ float lds[LROWS * STRIP];   // 35 KB -> 4 blocks/CU

    const int tid  = threadIdx.x;
    const int lane = tid & 63;
    const int wv   = tid >> 6;

    const int bid    = blockIdx.x;
    const int strip  = bid & (NSTRIP - 1);
    const int lchunk = (bid >> 3) & (NCHUNK - 1);
    const int b      = bid >> 10;

    const int l0 = lchunk * ROWS;
    const int c0 = strip * STRIP;

    const float* xs = x + (size_t)b * CL * CD + c0;   // strip base, row stride CD
    float*       ys = y + (size_t)b * CL * CD + c0;

    // Zero the 3 causal-halo rows for the first chunk (768 float4 = 192 threads).
    // Wave-uniform branch (waves 0-2 all true, wave 3 all false).
    if (l0 == 0 && tid < HALO * SF4) {
        ((float4*)lds)[tid] = make_float4(0.f, 0.f, 0.f, 0.f);
    }

    // ---- Stage LROWS row-strips: LDS row r <- global row (l0 - 3 + r). ----
    // One wave-instruction moves one full 1 KB row-strip (lane i -> base+16i).
    // Fire-and-forget: ~9 KB outstanding per wave, no destination VGPRs.
    for (int r = wv; r < LROWS; r += 4) {
        const int l = l0 - HALO + r;               // wave-uniform
        if (l >= 0) {
            const float* gsrc = xs + (size_t)l * CD + lane * 4;
            float* ldst = &lds[r * STRIP + lane * 4];
            __builtin_amdgcn_global_load_lds(
                (const __attribute__((address_space(1))) uint32_t*)gsrc,
                (__attribute__((address_space(3))) uint32_t*)ldst,
                16, 0, 0);
        }
    }

    // Per-lane weights/bias for columns c0 + lane*4 .. +3 (L2-resident, tiny).
    const float4 w0 = *(const float4*)(w + 0 * CD + c0 + lane * 4);
    const float4 w1 = *(const float4*)(w + 1 * CD + c0 + lane * 4);
    const float4 w2 = *(const float4*)(w + 2 * CD + c0 + lane * 4);
    const float4 w3 = *(const float4*)(w + 3 * CD + c0 + lane * 4);
    const float4 bv = *(const float4*)(bias + c0 + lane * 4);

    __syncthreads();   // drains vmcnt (load_lds) + lgkmcnt (halo zeros)

    // ---- Compute: wave wv owns output rows wv*8 .. wv*8+7. ----
    // Register sliding window: 11 ds_read_b128 per wave for 8 outputs.
    const int o0 = wv * 8;
    const float4* lrow = (const float4*)lds + lane;     // row stride SF4

    float4 xm3 = lrow[(o0 + 0) * SF4];
    float4 xm2 = lrow[(o0 + 1) * SF4];
    float4 xm1 = lrow[(o0 + 2) * SF4];

#pragma unroll
    for (int t = 0; t < 8; ++t) {
        const float4 a0 = lrow[(o0 + t + HALO) * SF4];

        nfloat4 r;
        r.x = fmaf(w0.x, xm3.x, fmaf(w1.x, xm2.x, fmaf(w2.x, xm1.x, fmaf(w3.x, a0.x, bv.x))));
        r.y = fmaf(w0.y, xm3.y, fmaf(w1.y, xm2.y, fmaf(w2.y, xm1.y, fmaf(w3.y, a0.y, bv.y))));
        r.z = fmaf(w0.z, xm3.z, fmaf(w1.z, xm2.z, fmaf(w2.z, xm1.z, fmaf(w3.z, a0.z, bv.z))));
        r.w = fmaf(w0.w, xm3.w, fmaf(w1.w, xm2.w, fmaf(w2.w, xm1.w, fmaf(w3.w, a0.w, bv.w))));

        const int l = l0 + o0 + t;
        __builtin_nontemporal_store(r, (nfloat4*)(ys + (size_t)l * CD + lane * 4));

        xm3 = xm2;
        xm2 = xm1;
        xm1 = a0;
    }
}

extern "C" void kernel_launch(void* const* d_in, const int* in_sizes, int n_in,
                              void* d_out, int out_size, void* d_ws, size_t ws_size,
                              hipStream_t stream) {
    const float* x = (const float*)d_in[0];
    const float* w = (const float*)d_in[1];
    const float* b = (const float*)d_in[2];
    float* y = (float*)d_out;

    const int grid = CB * NCHUNK * NSTRIP;   // 4 * 128 * 8 = 4096 blocks
    short_conv_kernel<<<grid, 256, 0, stream>>>(x, w, b, y);
}